// Round 20
// baseline (66.992 us; speedup 1.0000x reference)
//
#include <hip/hip_runtime.h>

#define B_TOT 2048
#define NHEAD 3

typedef __attribute__((ext_vector_type(8))) short short8v;
typedef __attribute__((ext_vector_type(4))) float f32x4;
typedef __attribute__((ext_vector_type(2))) __fp16 f16x2;

typedef __attribute__((address_space(1))) const void* gas_ptr;
typedef __attribute__((address_space(3))) void* las_ptr;

#define LOG2E 1.4426950408889634f

static __device__ __forceinline__ unsigned short f2bf(float x) {
    unsigned u = __builtin_bit_cast(unsigned, x);
    u += 0x7FFFu + ((u >> 16) & 1u);
    return (unsigned short)(u >> 16);
}
static __device__ __forceinline__ float bf2f(unsigned short s) {
    unsigned u = ((unsigned)s) << 16;
    return __builtin_bit_cast(float, u);
}
static __device__ __forceinline__ float exp2_fast(float x) {
    float r; asm("v_exp_f32 %0, %1" : "=v"(r) : "v"(x)); return r;
}

// ---------------------------------------------------------------------------
// Bias MLP precompute, 4-way j-split (verified r17/r19). Layout (r7-r19):
//   bias2[((h*16 + mt*4 + nt) * 64 + lane) * 4 + r], pre-scaled by log2e.
// ---------------------------------------------------------------------------
__global__ __launch_bounds__(256) void bias_kernel(const float* __restrict__ w1,
                                                   const float* __restrict__ b1,
                                                   const float* __restrict__ w2,
                                                   const float* __restrict__ b2,
                                                   float* __restrict__ bias2) {
    int gtid = blockIdx.x * 256 + threadIdx.x;   // 0..49151
    int t = gtid >> 2, sub = gtid & 3;           // t: output index 0..12287
    int h = t >> 12;
    int lane = (t >> 6) & 63;
    int pair = t & 63;
    int g = lane >> 4, c = lane & 15;
    int mt = pair >> 4, nt = (pair >> 2) & 3, r = pair & 3;
    int n = 16 * mt + 4 * g + r;
    int m = 16 * nt + c;

    float d0 = (float)((n >> 3) - (m >> 3));
    float d1 = (float)((n & 7) - (m & 7));
    float r0 = (d0 > 0.f ? 1.f : (d0 < 0.f ? -1.f : 0.f)) * log1pf(fabsf(d0));
    float r1 = (d1 > 0.f ? 1.f : (d1 < 0.f ? -1.f : 0.f)) * log1pf(fabsf(d1));
    float a = 0.f;
    for (int i = 0; i < 64; i++) {
        int j = 4 * i + sub;
        float hd = fmaf(r0, w1[j], fmaf(r1, w1[256 + j], b1[j]));
        hd = fmaxf(hd, 0.f);
        a = fmaf(hd, w2[j * 3 + h], a);
    }
    a += __shfl_xor(a, 1, 64);
    a += __shfl_xor(a, 2, 64);
    if (sub == 0)
        bias2[((h * 16 + mt * 4 + nt) * 64 + lane) * 4 + r] = (a + b2[h]) * LOG2E;
}

// ---------------------------------------------------------------------------
// Main kernel = round-19 verified pipeline (60.6us) + V staged at the head:
//  (1) V: 8x global_load_lds into Vs [64][32] f32, issued IN THE SAME latency
//      window as the k-stage (one vmcnt(0) covers k+V+q). Global source is
//      pre-swizzled (dword-XOR col ^ 4*(row&7)) so LDS holds a swizzled V;
//      reads apply the same XOR (rule-21 both-sides pattern). This removes
//      both mid-kernel VMEM windows (vr 8xb128 + vb 32 scalars).
//  (2) Vp (PV B-frags) packed straight from LDS after the P barrier — kills
//      the 32-reg vb live range.
// LDS 17408B/wave (Qs 9216 + Vs 8192) = 69632/block -> 2 blocks/CU, matching
// launch_bounds(256,2)'s cap (VGPR 128; r17/r18 showed tighter caps spill).
// ---------------------------------------------------------------------------
__global__ __launch_bounds__(256, 2) void attn_kernel(const float* __restrict__ qkv,
                                                      const float* __restrict__ bias2,
                                                      float* __restrict__ out) {
    // per-wave: Qs 2304 floats (k [64][32] -> q [64][36] -> O -> P bf16 overlay)
    //           Vs 2048 floats (swizzled V, persistent)
    __shared__ float smem[4][2304 + 2048];

    const int t = threadIdx.x;
    const int w = t >> 6;
    const int lane = t & 63;
    const int h = blockIdx.x % 3;
    const int b = (blockIdx.x / 3) * 4 + w;

    float* Qs = smem[w];
    float* Vs = Qs + 2304;
    const float* base = qkv + (size_t)b * (64 * 288) + h * 32;
    const float QS = 0.17677669529663687f * LOG2E;   // 32^-0.5 * log2e
    const int dd = lane & 31, H2 = lane >> 5;
    const int g = lane >> 4, c = lane & 15;
    const int nr = lane >> 3, d0q = (lane & 7) * 4;

    // ---- k: HBM -> LDS direct (linear [64][32]); V: HBM -> LDS direct with
    // pre-swizzled global source (LDS[row][col] = V[row][col ^ 4*(row&7)]) ----
    #pragma unroll
    for (int s = 0; s < 8; s++) {
        const float* gk = base + (8 * s + nr) * 288 + 96 + d0q;
        __builtin_amdgcn_global_load_lds((gas_ptr)gk, (las_ptr)(Qs + s * 256),
                                         16, 0, 0);
        const float* gv = base + (8 * s + nr) * 288 + 192 + (d0q ^ (4 * nr));
        __builtin_amdgcn_global_load_lds((gas_ptr)gv, (las_ptr)(Vs + s * 256),
                                         16, 0, 0);
    }

    // ---- q global loads in the same window, kept in regs ----
    float4 qreg[8];
    #pragma unroll
    for (int s = 0; s < 8; s++)
        qreg[s] = *(const float4*)(base + (8 * s + nr) * 288 + d0q);

    asm volatile("s_waitcnt vmcnt(0)" ::: "memory");

    // ---- krp from LDS k, rows rotated by 4*H2: krp[t8][i]={k[i],k[(i-1)&7]} ----
    f16x2 krp[64];
    #pragma unroll
    for (int t8 = 0; t8 < 8; t8++) {
        const int rb = ((t8 + 4 * H2) & 7) * 8;
        float k8[8];
        #pragma unroll
        for (int tx = 0; tx < 8; tx++)
            k8[tx] = Qs[(rb + tx) * 32 + dd];
        #pragma unroll
        for (int i = 0; i < 8; i++)
            krp[t8 * 8 + i] = __builtin_amdgcn_cvt_pkrtz(k8[i], k8[(i - 1) & 7]);
    }
    __builtin_amdgcn_sched_barrier(0);

    // ---- q -> LDS (scaled) [64][36], overwrites k region (DS-FIFO safe) ----
    #pragma unroll
    for (int s = 0; s < 8; s++) {
        float4 q4 = qreg[s];
        q4.x *= QS; q4.y *= QS; q4.z *= QS; q4.w *= QS;
        *(float4*)(Qs + (8 * s + nr) * 36 + d0q) = q4;
    }
    asm volatile("s_waitcnt lgkmcnt(0)" ::: "memory");

    // ---- stage 1: 8x8 cyclic conv via f16 dot2, f32 accumulate ----
    float acc[4][8];
    #pragma unroll
    for (int yi = 0; yi < 4; yi++)
        #pragma unroll
        for (int x = 0; x < 8; x++) acc[yi][x] = 0.f;

    #pragma unroll
    for (int u = 0; u < 8; u++) {
        f16x2 q2[4];
        #pragma unroll
        for (int j = 0; j < 4; j++) {
            float qa = Qs[(u * 8 + 2 * j) * 36 + dd];
            float qb = Qs[(u * 8 + 2 * j + 1) * 36 + dd];
            q2[j] = __builtin_amdgcn_cvt_pkrtz(qa, qb);
        }
        #pragma unroll
        for (int yi = 0; yi < 4; yi++) {
            const int s = (yi - u) & 7;
            #pragma unroll
            for (int x = 0; x < 8; x++) {
                #pragma unroll
                for (int j = 0; j < 4; j++)
                    acc[yi][x] = __builtin_amdgcn_fdot2(
                        q2[j], krp[s * 8 + ((x - 2 * j) & 7)], acc[yi][x], false);
            }
        }
    }

    // ---- O into Qs region ----
    #pragma unroll
    for (int yi = 0; yi < 4; yi++) {
        const int n = (4 * H2 + yi) * 8;
        #pragma unroll
        for (int x = 0; x < 8; x++)
            Qs[(n + x) * 36 + dd] = acc[yi][x];
    }
    asm volatile("s_waitcnt lgkmcnt(0)" ::: "memory");

    // ---- A-frags of O (hi/lo bf16): row = 16*mt + c, k-chunk = 8*g ----
    short8v Oh[4], Ol[4];
    #pragma unroll
    for (int mt = 0; mt < 4; mt++) {
        const float* rp = Qs + (16 * mt + c) * 36 + 8 * g;
        float4 x0 = *(const float4*)rp;
        float4 x1 = *(const float4*)(rp + 4);
        float xs[8] = {x0.x, x0.y, x0.z, x0.w, x1.x, x1.y, x1.z, x1.w};
        #pragma unroll
        for (int j = 0; j < 8; j++) {
            unsigned short hb = f2bf(xs[j]);
            Oh[mt][j] = (short)hb;
            Ol[mt][j] = (short)f2bf(xs[j] - bf2f(hb));
        }
    }

    // ---- B-frags of V^T (hi/lo) from swizzled LDS: row = 16*nt + c ----
    short8v Vh[4], Vl[4];
    {
        const int xorv = 4 * (c & 7);   // row&7 == c&7
        #pragma unroll
        for (int nt = 0; nt < 4; nt++) {
            const float* rp = Vs + (16 * nt + c) * 32;
            float4 x0 = *(const float4*)(rp + ((8 * g) ^ xorv));
            float4 x1 = *(const float4*)(rp + ((8 * g + 4) ^ xorv));
            float xs[8] = {x0.x, x0.y, x0.z, x0.w, x1.x, x1.y, x1.z, x1.w};
            #pragma unroll
            for (int j = 0; j < 8; j++) {
                unsigned short hb = f2bf(xs[j]);
                Vh[nt][j] = (short)hb;
                Vl[nt][j] = (short)f2bf(xs[j] - bf2f(hb));
            }
        }
    }

    // ---- S = O * V^T via MFMA (bias C-init; hh+hl+lh ~= fp32) ----
    const float* bb = bias2 + (size_t)h * 16 * 256 + lane * 4;
    f32x4 S[4][4];
    __builtin_amdgcn_s_setprio(1);
    #pragma unroll
    for (int mt = 0; mt < 4; mt++)
        #pragma unroll
        for (int nt = 0; nt < 4; nt++) {
            f32x4 a = __builtin_bit_cast(f32x4, *(const float4*)(bb + (mt * 4 + nt) * 256));
            a = __builtin_amdgcn_mfma_f32_16x16x32_bf16(Oh[mt], Vh[nt], a, 0, 0, 0);
            a = __builtin_amdgcn_mfma_f32_16x16x32_bf16(Oh[mt], Vl[nt], a, 0, 0, 0);
            a = __builtin_amdgcn_mfma_f32_16x16x32_bf16(Ol[mt], Vh[nt], a, 0, 0, 0);
            S[mt][nt] = a;
        }
    __builtin_amdgcn_s_setprio(0);

    // ---- softmax: max-subtract (shfl) + exp2; SUM deferred to ones-MFMA ----
    #pragma unroll
    for (int mt = 0; mt < 4; mt++) {
        #pragma unroll
        for (int r = 0; r < 4; r++) {
            float m0 = fmaxf(fmaxf(S[mt][0][r], S[mt][1][r]), fmaxf(S[mt][2][r], S[mt][3][r]));
            m0 = fmaxf(m0, __shfl_xor(m0, 1, 64));
            m0 = fmaxf(m0, __shfl_xor(m0, 2, 64));
            m0 = fmaxf(m0, __shfl_xor(m0, 4, 64));
            m0 = fmaxf(m0, __shfl_xor(m0, 8, 64));
            #pragma unroll
            for (int nt = 0; nt < 4; nt++)
                S[mt][nt][r] = exp2_fast(S[mt][nt][r] - m0);
        }
    }

    // ---- P (unnormalized, <=1) -> LDS bf16 [64][72] (aliases O; O consumed) ----
    unsigned short* Ps = (unsigned short*)Qs;
    #pragma unroll
    for (int mt = 0; mt < 4; mt++)
        #pragma unroll
        for (int nt = 0; nt < 4; nt++)
            #pragma unroll
            for (int r = 0; r < 4; r++)
                Ps[(16 * mt + 4 * g + r) * 72 + 16 * nt + c] = f2bf(S[mt][nt][r]);
    asm volatile("s_waitcnt lgkmcnt(0)" ::: "memory");

    // ---- P A-frags: row = 16*mt + c, k-chunk = 32*kt + 8*g ----
    short8v Pf[4][2];
    #pragma unroll
    for (int mt = 0; mt < 4; mt++)
        #pragma unroll
        for (int kt = 0; kt < 2; kt++)
            Pf[mt][kt] = *(const short8v*)(Ps + (16 * mt + c) * 72 + 32 * kt + 8 * g);

    // ---- V B-frags for PV (single bf16) straight from swizzled LDS:
    // element V[32*kt+8*g+j][16*dt+c]; row&7 == j -> xor 4*j ----
    short8v Vp[2][2];
    #pragma unroll
    for (int kt = 0; kt < 2; kt++)
        #pragma unroll
        for (int dt = 0; dt < 2; dt++)
            #pragma unroll
            for (int j = 0; j < 8; j++)
                Vp[kt][dt][j] = (short)f2bf(
                    Vs[(32 * kt + 8 * g + j) * 32 + ((16 * dt + c) ^ (4 * j))]);

    // ---- row sums via ones-MFMA; inv via plain division (hazard-safe) ----
    short8v ones;
    #pragma unroll
    for (int j = 0; j < 8; j++) ones[j] = (short)0x3F80;   // bf16 1.0
    f32x4 inv4[4];
    __builtin_amdgcn_s_setprio(1);
    #pragma unroll
    for (int mt = 0; mt < 4; mt++) {
        f32x4 sa = {0.f, 0.f, 0.f, 0.f};
        sa = __builtin_amdgcn_mfma_f32_16x16x32_bf16(Pf[mt][0], ones, sa, 0, 0, 0);
        sa = __builtin_amdgcn_mfma_f32_16x16x32_bf16(Pf[mt][1], ones, sa, 0, 0, 0);
        #pragma unroll
        for (int r = 0; r < 4; r++) inv4[mt][r] = 1.f / sa[r];
    }

    // ---- X = P * V via MFMA ----
    f32x4 X[4][2];
    #pragma unroll
    for (int mt = 0; mt < 4; mt++)
        #pragma unroll
        for (int dt = 0; dt < 2; dt++) {
            f32x4 a = {0.f, 0.f, 0.f, 0.f};
            a = __builtin_amdgcn_mfma_f32_16x16x32_bf16(Pf[mt][0], Vp[0][dt], a, 0, 0, 0);
            a = __builtin_amdgcn_mfma_f32_16x16x32_bf16(Pf[mt][1], Vp[1][dt], a, 0, 0, 0);
            X[mt][dt] = a;
        }
    __builtin_amdgcn_s_setprio(0);

    // ---- normalize + store: out[b][n][h*32 + d] ----
    float* op = out + (size_t)b * (64 * 96) + h * 32;
    #pragma unroll
    for (int mt = 0; mt < 4; mt++)
        #pragma unroll
        for (int dt = 0; dt < 2; dt++)
            #pragma unroll
            for (int r = 0; r < 4; r++)
                op[(16 * mt + 4 * g + r) * 96 + 16 * dt + c] = X[mt][dt][r] * inv4[mt][r];
}

extern "C" void kernel_launch(void* const* d_in, const int* in_sizes, int n_in,
                              void* d_out, int out_size, void* d_ws, size_t ws_size,
                              hipStream_t stream) {
    const float* qkv = (const float*)d_in[0];
    const float* w1  = (const float*)d_in[1];
    const float* b1  = (const float*)d_in[2];
    const float* w2  = (const float*)d_in[3];
    const float* b2  = (const float*)d_in[4];
    float* out = (float*)d_out;
    float* bias2 = (float*)d_ws;   // 48 KB

    bias_kernel<<<192, 256, 0, stream>>>(w1, b1, w2, b2, bias2);
    attn_kernel<<<(B_TOT / 4) * NHEAD, 256, 0, stream>>>(qkv, bias2, out);
}

// Round 21
// 57.443 us; speedup vs baseline: 1.1662x; 1.1662x over previous
//
#include <hip/hip_runtime.h>

#define B_TOT 2048
#define NHEAD 3

typedef __attribute__((ext_vector_type(8))) short short8v;
typedef __attribute__((ext_vector_type(4))) float f32x4;
typedef __attribute__((ext_vector_type(2))) __fp16 f16x2;

typedef __attribute__((address_space(1))) const void* gas_ptr;
typedef __attribute__((address_space(3))) void* las_ptr;

#define LOG2E 1.4426950408889634f

static __device__ __forceinline__ unsigned short f2bf(float x) {
    unsigned u = __builtin_bit_cast(unsigned, x);
    u += 0x7FFFu + ((u >> 16) & 1u);
    return (unsigned short)(u >> 16);
}
static __device__ __forceinline__ float bf2f(unsigned short s) {
    unsigned u = ((unsigned)s) << 16;
    return __builtin_bit_cast(float, u);
}
static __device__ __forceinline__ float exp2_fast(float x) {
    float r; asm("v_exp_f32 %0, %1" : "=v"(r) : "v"(x)); return r;
}

// ---------------------------------------------------------------------------
// Bias MLP precompute, 16-way j-split (768 blocks; 16 threads per output,
// 4-shfl reduce). Output layout unchanged (verified r7-r20):
//   bias2[((h*16 + mt*4 + nt) * 64 + lane) * 4 + r], pre-scaled by log2e.
// ---------------------------------------------------------------------------
__global__ __launch_bounds__(256) void bias_kernel(const float* __restrict__ w1,
                                                   const float* __restrict__ b1,
                                                   const float* __restrict__ w2,
                                                   const float* __restrict__ b2,
                                                   float* __restrict__ bias2) {
    int gtid = blockIdx.x * 256 + threadIdx.x;   // 0..196607
    int t = gtid >> 4, sub = gtid & 15;          // t: output index 0..12287
    int h = t >> 12;
    int lane = (t >> 6) & 63;
    int pair = t & 63;
    int g = lane >> 4, c = lane & 15;
    int mt = pair >> 4, nt = (pair >> 2) & 3, r = pair & 3;
    int n = 16 * mt + 4 * g + r;
    int m = 16 * nt + c;

    float d0 = (float)((n >> 3) - (m >> 3));
    float d1 = (float)((n & 7) - (m & 7));
    float r0 = (d0 > 0.f ? 1.f : (d0 < 0.f ? -1.f : 0.f)) * log1pf(fabsf(d0));
    float r1 = (d1 > 0.f ? 1.f : (d1 < 0.f ? -1.f : 0.f)) * log1pf(fabsf(d1));
    float a = 0.f;
    #pragma unroll
    for (int i = 0; i < 16; i++) {
        int j = 16 * i + sub;
        float hd = fmaf(r0, w1[j], fmaf(r1, w1[256 + j], b1[j]));
        hd = fmaxf(hd, 0.f);
        a = fmaf(hd, w2[j * 3 + h], a);
    }
    a += __shfl_xor(a, 1, 64);
    a += __shfl_xor(a, 2, 64);
    a += __shfl_xor(a, 4, 64);
    a += __shfl_xor(a, 8, 64);
    if (sub == 0)
        bias2[((h * 16 + mt * 4 + nt) * 64 + lane) * 4 + r] = (a + b2[h]) * LOG2E;
}

// ---------------------------------------------------------------------------
// Main kernel = round-19 verified pipeline (60.6us) + XCD-aware block swizzle:
// blocks 3k..3k+2 read the SAME 4 batches; the bijective remap
// bid = (i%8)*192 + i/8 puts consecutive logical blocks on ONE XCD so their
// shared qkv lines are L2-hits (~200cy) instead of L3 re-fetches (~450cy) —
// a direct cut to the latency-bound head window. (nwg=1536, 1536%8==0.)
// Everything else byte-identical to r19.
// ---------------------------------------------------------------------------
__global__ __launch_bounds__(256, 2) void attn_kernel(const float* __restrict__ qkv,
                                                      const float* __restrict__ bias2,
                                                      float* __restrict__ out) {
    // per-wave 9216B region: k [64][32] f32 (linear) -> q [64][36] f32
    //                        -> O [64][36] f32 -> P [64][72] bf16
    __shared__ float smem[4][64 * 36];

    const int t = threadIdx.x;
    const int w = t >> 6;
    const int lane = t & 63;
    const int bid = (blockIdx.x & 7) * 192 + (blockIdx.x >> 3);   // XCD swizzle
    const int h = bid % 3;
    const int b = (bid / 3) * 4 + w;

    float* Qs = smem[w];
    const float* base = qkv + (size_t)b * (64 * 288) + h * 32;
    const float QS = 0.17677669529663687f * LOG2E;   // 32^-0.5 * log2e
    const int dd = lane & 31, H2 = lane >> 5;
    const int g = lane >> 4, c = lane & 15;
    const int nr = lane >> 3, d0q = (lane & 7) * 4;

    // ---- k: HBM -> LDS direct, 8x global_load_lds (16B/lane, 1KB/instr).
    // LDS linear [64][32]: call s covers rows 8s..8s+7. ----
    #pragma unroll
    for (int s = 0; s < 8; s++) {
        const float* gsrc = base + (8 * s + nr) * 288 + 96 + d0q;
        __builtin_amdgcn_global_load_lds((gas_ptr)gsrc, (las_ptr)(Qs + s * 256),
                                         16, 0, 0);
    }

    // ---- q global loads issued now (share the latency window), kept in regs ----
    float4 qreg[8];
    #pragma unroll
    for (int s = 0; s < 8; s++)
        qreg[s] = *(const float4*)(base + (8 * s + nr) * 288 + d0q);

    asm volatile("s_waitcnt vmcnt(0)" ::: "memory");

    // ---- krp from LDS k (pipelined ds_reads), rows rotated by 4*H2:
    // krp[t8][i] = {k[i], k[(i-1)&7]} (f16x2) ----
    f16x2 krp[64];
    #pragma unroll
    for (int t8 = 0; t8 < 8; t8++) {
        const int rb = ((t8 + 4 * H2) & 7) * 8;
        float k8[8];
        #pragma unroll
        for (int tx = 0; tx < 8; tx++)
            k8[tx] = Qs[(rb + tx) * 32 + dd];
        #pragma unroll
        for (int i = 0; i < 8; i++)
            krp[t8 * 8 + i] = __builtin_amdgcn_cvt_pkrtz(k8[i], k8[(i - 1) & 7]);
    }
    __builtin_amdgcn_sched_barrier(0);

    // ---- q -> LDS (scaled) [64][36], overwrites k region (DS-FIFO safe) ----
    #pragma unroll
    for (int s = 0; s < 8; s++) {
        float4 q4 = qreg[s];
        q4.x *= QS; q4.y *= QS; q4.z *= QS; q4.w *= QS;
        *(float4*)(Qs + (8 * s + nr) * 36 + d0q) = q4;
    }
    asm volatile("s_waitcnt lgkmcnt(0)" ::: "memory");

    // ---- stage 1: 8x8 cyclic conv via f16 dot2, f32 accumulate ----
    float acc[4][8];
    #pragma unroll
    for (int yi = 0; yi < 4; yi++)
        #pragma unroll
        for (int x = 0; x < 8; x++) acc[yi][x] = 0.f;

    #pragma unroll
    for (int u = 0; u < 8; u++) {
        f16x2 q2[4];
        #pragma unroll
        for (int j = 0; j < 4; j++) {
            float qa = Qs[(u * 8 + 2 * j) * 36 + dd];
            float qb = Qs[(u * 8 + 2 * j + 1) * 36 + dd];
            q2[j] = __builtin_amdgcn_cvt_pkrtz(qa, qb);
        }
        #pragma unroll
        for (int yi = 0; yi < 4; yi++) {
            const int s = (yi - u) & 7;
            #pragma unroll
            for (int x = 0; x < 8; x++) {
                #pragma unroll
                for (int j = 0; j < 4; j++)
                    acc[yi][x] = __builtin_amdgcn_fdot2(
                        q2[j], krp[s * 8 + ((x - 2 * j) & 7)], acc[yi][x], false);
            }
        }
    }

    // ---- O into same LDS region ----
    #pragma unroll
    for (int yi = 0; yi < 4; yi++) {
        const int n = (4 * H2 + yi) * 8;
        #pragma unroll
        for (int x = 0; x < 8; x++)
            Qs[(n + x) * 36 + dd] = acc[yi][x];
    }
    asm volatile("s_waitcnt lgkmcnt(0)" ::: "memory");

    // ---- A-frags of O (hi/lo bf16): row = 16*mt + c, k-chunk = 8*g ----
    short8v Oh[4], Ol[4];
    #pragma unroll
    for (int mt = 0; mt < 4; mt++) {
        const float* rp = Qs + (16 * mt + c) * 36 + 8 * g;
        float4 x0 = *(const float4*)rp;
        float4 x1 = *(const float4*)(rp + 4);
        float xs[8] = {x0.x, x0.y, x0.z, x0.w, x1.x, x1.y, x1.z, x1.w};
        #pragma unroll
        for (int j = 0; j < 8; j++) {
            unsigned short hb = f2bf(xs[j]);
            Oh[mt][j] = (short)hb;
            Ol[mt][j] = (short)f2bf(xs[j] - bf2f(hb));
        }
    }

    // ---- B-frags of V^T (hi/lo): element V[16*nt + c][8*g + j], from global ----
    short8v Vh[4], Vl[4];
    #pragma unroll
    for (int nt = 0; nt < 4; nt++) {
        const float* vp = base + (16 * nt + c) * 288 + 192 + 8 * g;
        float4 x0 = *(const float4*)vp;
        float4 x1 = *(const float4*)(vp + 4);
        float xs[8] = {x0.x, x0.y, x0.z, x0.w, x1.x, x1.y, x1.z, x1.w};
        #pragma unroll
        for (int j = 0; j < 8; j++) {
            unsigned short hb = f2bf(xs[j]);
            Vh[nt][j] = (short)hb;
            Vl[nt][j] = (short)f2bf(xs[j] - bf2f(hb));
        }
    }

    // ---- S = O * V^T via MFMA (bias C-init; hh+hl+lh ~= fp32) ----
    const float* bb = bias2 + (size_t)h * 16 * 256 + lane * 4;
    f32x4 S[4][4];
    __builtin_amdgcn_s_setprio(1);
    #pragma unroll
    for (int mt = 0; mt < 4; mt++)
        #pragma unroll
        for (int nt = 0; nt < 4; nt++) {
            f32x4 a = __builtin_bit_cast(f32x4, *(const float4*)(bb + (mt * 4 + nt) * 256));
            a = __builtin_amdgcn_mfma_f32_16x16x32_bf16(Oh[mt], Vh[nt], a, 0, 0, 0);
            a = __builtin_amdgcn_mfma_f32_16x16x32_bf16(Oh[mt], Vl[nt], a, 0, 0, 0);
            a = __builtin_amdgcn_mfma_f32_16x16x32_bf16(Ol[mt], Vh[nt], a, 0, 0, 0);
            S[mt][nt] = a;
        }
    __builtin_amdgcn_s_setprio(0);

    // ---- prefetch V for PV stage (raw f32, packed later) ----
    float vb[2][2][8];   // [kt][dt][j] = V[32*kt + 8*g + j][16*dt + c]
    #pragma unroll
    for (int kt = 0; kt < 2; kt++)
        #pragma unroll
        for (int dt = 0; dt < 2; dt++)
            #pragma unroll
            for (int j = 0; j < 8; j++)
                vb[kt][dt][j] = base[(32 * kt + 8 * g + j) * 288 + 192 + 16 * dt + c];

    // ---- softmax: max-subtract (shfl) + exp2; SUM deferred to ones-MFMA ----
    #pragma unroll
    for (int mt = 0; mt < 4; mt++) {
        #pragma unroll
        for (int r = 0; r < 4; r++) {
            float m0 = fmaxf(fmaxf(S[mt][0][r], S[mt][1][r]), fmaxf(S[mt][2][r], S[mt][3][r]));
            m0 = fmaxf(m0, __shfl_xor(m0, 1, 64));
            m0 = fmaxf(m0, __shfl_xor(m0, 2, 64));
            m0 = fmaxf(m0, __shfl_xor(m0, 4, 64));
            m0 = fmaxf(m0, __shfl_xor(m0, 8, 64));
            #pragma unroll
            for (int nt = 0; nt < 4; nt++)
                S[mt][nt][r] = exp2_fast(S[mt][nt][r] - m0);
        }
    }

    // ---- P (unnormalized, <=1) -> LDS bf16 [64][72] (aliases O; O consumed) ----
    unsigned short* Ps = (unsigned short*)Qs;
    #pragma unroll
    for (int mt = 0; mt < 4; mt++)
        #pragma unroll
        for (int nt = 0; nt < 4; nt++)
            #pragma unroll
            for (int r = 0; r < 4; r++)
                Ps[(16 * mt + 4 * g + r) * 72 + 16 * nt + c] = f2bf(S[mt][nt][r]);
    asm volatile("s_waitcnt lgkmcnt(0)" ::: "memory");

    // ---- P A-frags: row = 16*mt + c, k-chunk = 32*kt + 8*g ----
    short8v Pf[4][2];
    #pragma unroll
    for (int mt = 0; mt < 4; mt++)
        #pragma unroll
        for (int kt = 0; kt < 2; kt++)
            Pf[mt][kt] = *(const short8v*)(Ps + (16 * mt + c) * 72 + 32 * kt + 8 * g);

    // ---- V B-frags for PV (single bf16) ----
    short8v Vp[2][2];
    #pragma unroll
    for (int kt = 0; kt < 2; kt++)
        #pragma unroll
        for (int dt = 0; dt < 2; dt++)
            #pragma unroll
            for (int j = 0; j < 8; j++)
                Vp[kt][dt][j] = (short)f2bf(vb[kt][dt][j]);

    // ---- row sums via ones-MFMA; inv via plain division (hazard-safe) ----
    short8v ones;
    #pragma unroll
    for (int j = 0; j < 8; j++) ones[j] = (short)0x3F80;   // bf16 1.0
    f32x4 inv4[4];
    __builtin_amdgcn_s_setprio(1);
    #pragma unroll
    for (int mt = 0; mt < 4; mt++) {
        f32x4 sa = {0.f, 0.f, 0.f, 0.f};
        sa = __builtin_amdgcn_mfma_f32_16x16x32_bf16(Pf[mt][0], ones, sa, 0, 0, 0);
        sa = __builtin_amdgcn_mfma_f32_16x16x32_bf16(Pf[mt][1], ones, sa, 0, 0, 0);
        #pragma unroll
        for (int r = 0; r < 4; r++) inv4[mt][r] = 1.f / sa[r];
    }

    // ---- X = P * V via MFMA ----
    f32x4 X[4][2];
    #pragma unroll
    for (int mt = 0; mt < 4; mt++)
        #pragma unroll
        for (int dt = 0; dt < 2; dt++) {
            f32x4 a = {0.f, 0.f, 0.f, 0.f};
            a = __builtin_amdgcn_mfma_f32_16x16x32_bf16(Pf[mt][0], Vp[0][dt], a, 0, 0, 0);
            a = __builtin_amdgcn_mfma_f32_16x16x32_bf16(Pf[mt][1], Vp[1][dt], a, 0, 0, 0);
            X[mt][dt] = a;
        }
    __builtin_amdgcn_s_setprio(0);

    // ---- normalize + store: out[b][n][h*32 + d] ----
    float* op = out + (size_t)b * (64 * 96) + h * 32;
    #pragma unroll
    for (int mt = 0; mt < 4; mt++)
        #pragma unroll
        for (int dt = 0; dt < 2; dt++)
            #pragma unroll
            for (int r = 0; r < 4; r++)
                op[(16 * mt + 4 * g + r) * 96 + 16 * dt + c] = X[mt][dt][r] * inv4[mt][r];
}

extern "C" void kernel_launch(void* const* d_in, const int* in_sizes, int n_in,
                              void* d_out, int out_size, void* d_ws, size_t ws_size,
                              hipStream_t stream) {
    const float* qkv = (const float*)d_in[0];
    const float* w1  = (const float*)d_in[1];
    const float* b1  = (const float*)d_in[2];
    const float* w2  = (const float*)d_in[3];
    const float* b2  = (const float*)d_in[4];
    float* out = (float*)d_out;
    float* bias2 = (float*)d_ws;   // 48 KB

    bias_kernel<<<768, 256, 0, stream>>>(w1, b1, w2, b2, bias2);
    attn_kernel<<<(B_TOT / 4) * NHEAD, 256, 0, stream>>>(qkv, bias2, out);
}